// Round 2
// baseline (608.396 us; speedup 1.0000x reference)
//
#include <hip/hip_runtime.h>

#define T_TOKENS 8192
#define MDIM 1024
#define NEXP 8
#define DFF_DIM 4096
#define CAP 1280

typedef __attribute__((ext_vector_type(8))) short short8;
typedef __attribute__((ext_vector_type(4))) float f32x4;

__device__ inline unsigned short f2bf(float f) {
  unsigned u = __float_as_uint(f);
  u = u + 0x7fffu + ((u >> 16) & 1u);
  return (unsigned short)(u >> 16);
}

// async global->LDS DMA, 16B per lane. LDS dst must be wave-uniform base;
// lane i's data lands at base + i*16B (guide §5, m97/m104).
__device__ __forceinline__ void async_ld16(const void* g, void* l) {
  __builtin_amdgcn_global_load_lds(
      (__attribute__((address_space(1))) void*)const_cast<void*>(g),
      (__attribute__((address_space(3))) void*)l, 16, 0, 0);
}

// ---------------- gating: logits in fp64, softmax top-1 ----------------
__global__ __launch_bounds__(64) void gate_kernel(const float* __restrict__ x,
    const float* __restrict__ wg, int* __restrict__ eidx, float* __restrict__ gate)
{
  const int t = blockIdx.x;
  const int lane = threadIdx.x;
  const float* xr = x + (size_t)t * MDIM;
  double acc[NEXP];
  #pragma unroll
  for (int e = 0; e < NEXP; ++e) acc[e] = 0.0;
  for (int m = lane; m < MDIM; m += 64) {
    double xv = (double)xr[m];
    const float* wr = wg + (size_t)m * NEXP;
    #pragma unroll
    for (int e = 0; e < NEXP; ++e) acc[e] += xv * (double)wr[e];
  }
  #pragma unroll
  for (int off = 32; off > 0; off >>= 1) {
    #pragma unroll
    for (int e = 0; e < NEXP; ++e) acc[e] += __shfl_down(acc[e], off);
  }
  if (lane == 0) {
    double mx = acc[0]; int idx = 0;
    #pragma unroll
    for (int e = 1; e < NEXP; ++e) if (acc[e] > mx) { mx = acc[e]; idx = e; }
    double s = 0.0;
    #pragma unroll
    for (int e = 0; e < NEXP; ++e) s += exp(acc[e] - mx);
    eidx[t] = idx;
    gate[t] = (float)(1.0 / s);   // softmax prob of argmax expert
  }
}

// ---------------- order-preserving capacity scan (single block) ----------------
__global__ __launch_bounds__(1024) void scan_kernel(const int* __restrict__ eidx,
    int* __restrict__ slot_token, int* __restrict__ filled)
{
  __shared__ int hist[16][NEXP];
  __shared__ int wpre[16][NEXP];
  __shared__ int rtot[NEXP];
  __shared__ int base[NEXP];
  const int tid = threadIdx.x;
  const int w = tid >> 6, lane = tid & 63;
  for (int i = tid; i < NEXP * CAP; i += 1024) slot_token[i] = -1;
  if (tid < NEXP) base[tid] = 0;
  __syncthreads();
  const unsigned long long lt = (1ull << lane) - 1ull;
  for (int r = 0; r < T_TOKENS / 1024; ++r) {
    const int t = r * 1024 + tid;
    const int e = eidx[t];
    unsigned long long bal[NEXP];
    #pragma unroll
    for (int ee = 0; ee < NEXP; ++ee) bal[ee] = __ballot(e == ee);
    const int rank = __popcll(bal[e] & lt);
    if (lane < NEXP) hist[w][lane] = __popcll(bal[lane]);
    __syncthreads();
    if (tid < 16 * NEXP) {
      int ww = tid >> 3, ee = tid & 7, s = 0;
      for (int j = 0; j < ww; ++j) s += hist[j][ee];
      wpre[ww][ee] = s;
    }
    if (tid < NEXP) {
      int s = 0;
      for (int j = 0; j < 16; ++j) s += hist[j][tid];
      rtot[tid] = s;
    }
    __syncthreads();
    const int pos = base[e] + wpre[w][e] + rank;
    if (pos < CAP) slot_token[e * CAP + pos] = t;
    __syncthreads();
    if (tid < NEXP) base[tid] += rtot[tid];
    __syncthreads();
  }
  if (tid < NEXP) filled[tid] = (base[tid] < CAP) ? base[tid] : CAP;
}

// ---------------- dispatch: gather kept tokens into [E,C,M] bf16 ----------------
__global__ __launch_bounds__(256) void dispatch_kernel(const float* __restrict__ x,
    const int* __restrict__ slot_token, unsigned short* __restrict__ Abuf)
{
  const int row = blockIdx.x;
  const int tid = threadIdx.x;
  const int t = slot_token[row];
  unsigned short* dst = Abuf + (size_t)row * MDIM + tid * 4;
  if (t < 0) {
    ushort4 z; z.x = 0; z.y = 0; z.z = 0; z.w = 0;
    *(ushort4*)dst = z;
  } else {
    const float4 v = *(const float4*)(x + (size_t)t * MDIM + tid * 4);
    ushort4 h;
    h.x = f2bf(v.x); h.y = f2bf(v.y); h.z = f2bf(v.z); h.w = f2bf(v.w);
    *(ushort4*)dst = h;
  }
}

// ------------- weight transpose + fp32->bf16: src [R][Cc] -> dst [Cc][R] -------------
template<int R, int Cc>
__global__ __launch_bounds__(256) void transpose_cvt_kernel(
    const float* __restrict__ src, unsigned short* __restrict__ dst)
{
  __shared__ unsigned short tile[64][66];   // +2 pad: write-phase column reads ~2-way
  const int e = blockIdx.z;
  const int r0 = blockIdx.y * 64;
  const int c0 = blockIdx.x * 64;
  const int t = threadIdx.x;
  const float* S = src + (size_t)e * R * Cc;
  unsigned short* D = dst + (size_t)e * R * Cc;
  const int tr = t >> 4;         // 0..15
  const int tc = (t & 15) * 4;   // 0..60
  #pragma unroll
  for (int i = 0; i < 4; ++i) {
    const int row = i * 16 + tr;
    const float4 v = *(const float4*)(S + (size_t)(r0 + row) * Cc + c0 + tc);
    tile[row][tc + 0] = f2bf(v.x);
    tile[row][tc + 1] = f2bf(v.y);
    tile[row][tc + 2] = f2bf(v.z);
    tile[row][tc + 3] = f2bf(v.w);
  }
  __syncthreads();
  #pragma unroll
  for (int i = 0; i < 4; ++i) {
    const int crow = i * 16 + tr;   // src col index
    ushort4 o;
    o.x = tile[tc + 0][crow];
    o.y = tile[tc + 1][crow];
    o.z = tile[tc + 2][crow];
    o.w = tile[tc + 3][crow];
    *(ushort4*)(D + (size_t)(c0 + crow) * R + r0 + tc) = o;
  }
}

// =====================================================================
// GEMM1: H = relu(A @ W1T^T + b1), 256x256 tile, BK=32, 8 waves (2x4),
// 4 LDS buffers (128 KiB), counted-vmcnt pipeline (never vmcnt(0) in loop),
// T2 chunk swizzle, T5 setprio, T1 bijective XCD swizzle.
// (verified round 1; unchanged)
// =====================================================================
__global__ __launch_bounds__(512, 2) void gemm1_256(
    const unsigned short* __restrict__ A,   // [E][CAP][K] bf16
    const unsigned short* __restrict__ Bt,  // [E][N][K] bf16 (pre-transposed W1)
    const float* __restrict__ bias,         // [E][N]
    unsigned short* __restrict__ H,         // [E][CAP][N] bf16
    const int* __restrict__ filled)
{
  constexpr int N = DFF_DIM;   // 4096
  constexpr int K = MDIM;      // 1024
  constexpr int NT = K / 32;   // 32 k-tiles
  static_assert(CAP % 256 == 0, "row blocking");

  const int id = blockIdx.x;
  const int wk = (id & 7) * 80 + (id >> 3);
  const int e = wk / 80;
  const int rem = wk % 80;
  const int rowbase = (rem / 16) * 256;
  const int colbase = (rem % 16) * 256;
  if (rowbase >= filled[e]) return;   // block-uniform early exit (before barriers)

  __shared__ unsigned short lds[4 * 16384];

  const int tid = threadIdx.x;
  const int lane = tid & 63;
  const int wid = tid >> 6;         // 0..7
  const int wm = wid >> 2;          // 0..1 : 128-row half
  const int wn = wid & 3;           // 0..3 : 64-col slice
  const int qm = lane & 15;
  const int qr = lane >> 4;         // 0..3
  const int swc  = qr ^ ((qm >> 1) & 3);                 // read-side chunk
  const int srcc = (lane & 3) ^ ((lane >> 3) & 3);       // stage-side source chunk

  const unsigned short* Ab = A + ((size_t)e * CAP + rowbase) * K;
  const unsigned short* Bb = Bt + ((size_t)e * N + colbase) * K;

  const int srow = wid * 16 + (lane >> 2);               // 0..127 within unit
  const unsigned short* aU0 = Ab + (size_t)srow * K + srcc * 8;
  const unsigned short* aU1 = Ab + (size_t)(srow + 128) * K + srcc * 8;
  const unsigned short* bU0 = Bb + (size_t)srow * K + srcc * 8;
  const unsigned short* bU1 = Bb + (size_t)(srow + 128) * K + srcc * 8;

  f32x4 acc[8][4];
  #pragma unroll
  for (int i = 0; i < 8; ++i)
    #pragma unroll
    for (int j = 0; j < 4; ++j)
      #pragma unroll
      for (int r = 0; r < 4; ++r) acc[i][j][r] = 0.0f;

  #define STAGE_A(tt, bb) do { \
    const int k0_ = (tt) * 32; \
    unsigned short* l_ = lds + (bb) * 16384 + wid * 512; \
    async_ld16(aU0 + k0_, l_); \
    async_ld16(aU1 + k0_, l_ + 4096); \
  } while (0)
  #define STAGE_B(tt, bb) do { \
    const int k0_ = (tt) * 32; \
    unsigned short* l_ = lds + (bb) * 16384 + 8192 + wid * 512; \
    async_ld16(bU0 + k0_, l_); \
    async_ld16(bU1 + k0_, l_ + 4096); \
  } while (0)

  STAGE_A(0, 0); STAGE_B(0, 0);
  STAGE_A(1, 1); STAGE_B(1, 1);
  STAGE_A(2, 2); STAGE_B(2, 2);
  asm volatile("s_waitcnt vmcnt(8)" ::: "memory");   // tile 0 landed
  __builtin_amdgcn_s_barrier();

  for (int t = 0; t < NT; ++t) {
    const int buf = t & 3;
    const int pbuf = (t + 3) & 3;
    int ts = t + 3; if (ts >= NT) ts -= NT;
    const unsigned short* Ap = lds + buf * 16384;
    const unsigned short* Bp = Ap + 8192;
    short8 af[4], bfr[4];

    // ---- phase 0: C rows 0..63 of the wave's half ----
    #pragma unroll
    for (int i = 0; i < 4; ++i)
      af[i] = *(const short8*)(Ap + (wm * 128 + i * 16 + qm) * 32 + swc * 8);
    #pragma unroll
    for (int j = 0; j < 4; ++j)
      bfr[j] = *(const short8*)(Bp + (wn * 64 + j * 16 + qm) * 32 + swc * 8);
    STAGE_A(ts, pbuf);
    __builtin_amdgcn_s_barrier();
    asm volatile("s_waitcnt lgkmcnt(0)" ::: "memory");
    __builtin_amdgcn_sched_barrier(0);
    __builtin_amdgcn_s_setprio(1);
    #pragma unroll
    for (int i = 0; i < 4; ++i)
      #pragma unroll
      for (int j = 0; j < 4; ++j)
        acc[i][j] = __builtin_amdgcn_mfma_f32_16x16x32_bf16(af[i], bfr[j], acc[i][j], 0, 0, 0);
    __builtin_amdgcn_s_setprio(0);
    __builtin_amdgcn_s_barrier();

    // ---- phase 1: C rows 64..127 (reuse bfr, re-read af) ----
    #pragma unroll
    for (int i = 0; i < 4; ++i)
      af[i] = *(const short8*)(Ap + (wm * 128 + (i + 4) * 16 + qm) * 32 + swc * 8);
    STAGE_B(ts, pbuf);
    __builtin_amdgcn_s_barrier();
    asm volatile("s_waitcnt lgkmcnt(0)" ::: "memory");
    __builtin_amdgcn_sched_barrier(0);
    __builtin_amdgcn_s_setprio(1);
    #pragma unroll
    for (int i = 0; i < 4; ++i)
      #pragma unroll
      for (int j = 0; j < 4; ++j)
        acc[4 + i][j] = __builtin_amdgcn_mfma_f32_16x16x32_bf16(af[i], bfr[j], acc[4 + i][j], 0, 0, 0);
    __builtin_amdgcn_s_setprio(0);
    asm volatile("s_waitcnt vmcnt(8)" ::: "memory");   // tile t+1 guaranteed
    __builtin_amdgcn_s_barrier();
  }
  #undef STAGE_A
  #undef STAGE_B

  asm volatile("s_waitcnt vmcnt(0)" ::: "memory");

  float bcol[4];
  #pragma unroll
  for (int j = 0; j < 4; ++j)
    bcol[j] = bias[(size_t)e * N + colbase + wn * 64 + j * 16 + qm];

  #pragma unroll
  for (int i = 0; i < 8; ++i) {
    #pragma unroll
    for (int r = 0; r < 4; ++r) {
      const int row = rowbase + wm * 128 + i * 16 + qr * 4 + r;
      unsigned short* orow = H + ((size_t)e * CAP + row) * N + colbase;
      #pragma unroll
      for (int j = 0; j < 4; ++j) {
        float v = acc[i][j][r] + bcol[j];
        v = v > 0.0f ? v : 0.0f;
        orow[wn * 64 + j * 16 + qm] = f2bf(v);
      }
    }
  }
}

// =====================================================================
// GEMM2: out[token] = gate*(H @ W2T^T + b2).  NEW this round:
// 256x128 tile, BK=32, 512 threads (8 waves 2x4), 4 LDS buffers
// (4 x 24KiB = 96KiB), counted-vmcnt pipeline: 3 loads/thread/tile
// (A rows 0..127, A rows 128..255, B rows 0..127) -> steady-state
// vmcnt(6); never vmcnt(0) inside the loop.  Same T2 chunk swizzle,
// T5 setprio as gemm1_256.  T1: 320 blocks -> 40/XCD = one expert per
// XCD; rowbase fastest so 5 consecutive blocks share the 1MB B panel.
//
// Pipeline proof: tile t computes from buf[t&3]; stages tile t+3 into
// buf[(t+3)&3] whose prior content (tile t-1) was fully ds_read before
// the end-of-tile-(t-1) barrier -> no WAR race.  At tile t's end,
// outstanding loads <= tiles t+1,t+2,t+3 = 9; vmcnt(6) completes the
// oldest 3 = all of tile t+1; the s_barrier makes it cross-wave.
// =====================================================================
__global__ __launch_bounds__(512, 2) void gemm2_256(
    const unsigned short* __restrict__ A,   // [E][CAP][K] bf16  (H)
    const unsigned short* __restrict__ Bt,  // [E][N][K] bf16    (W2T: [M][DFF])
    const float* __restrict__ bias,         // [E][N]
    float* __restrict__ Op,
    const int* __restrict__ slot_token, const float* __restrict__ gate,
    const int* __restrict__ filled)
{
  constexpr int N = MDIM;      // 1024
  constexpr int K = DFF_DIM;   // 4096
  constexpr int NT = K / 32;   // 128 k-tiles

  const int id = blockIdx.x;            // 320 blocks: 8 colblk * 5 rowblk * 8 e
  const int wk = (id & 7) * 40 + (id >> 3);
  const int e = wk / 40;
  const int rem = wk % 40;
  const int colbase = (rem / 5) * 128;
  const int rowbase = (rem % 5) * 256;  // rowbase fastest: B col-panel L2-shared
  if (rowbase >= filled[e]) return;     // block-uniform early exit

  // 4 buffers x (A 16KB + B 8KB) = 96 KiB
  __shared__ unsigned short lds[4 * 12288];

  const int tid = threadIdx.x;
  const int lane = tid & 63;
  const int wid = tid >> 6;         // 0..7
  const int wm = wid >> 2;          // 0..1 : 128-row half
  const int wn = wid & 3;           // 0..3 : 32-col slice
  const int qm = lane & 15;
  const int qr = lane >> 4;         // 0..3
  const int swc  = qr ^ ((qm >> 1) & 3);                 // read-side chunk
  const int srcc = (lane & 3) ^ ((lane >> 3) & 3);       // stage-side source chunk

  const unsigned short* Ab = A + ((size_t)e * CAP + rowbase) * K;
  const unsigned short* Bb = Bt + ((size_t)e * N + colbase) * K;

  // staging unit = 128 rows x 32 k = 8 KB = 512 threads x 16 B
  const int srow = wid * 16 + (lane >> 2);               // 0..127 within unit
  const unsigned short* aU0 = Ab + (size_t)srow * K + srcc * 8;
  const unsigned short* aU1 = Ab + (size_t)(srow + 128) * K + srcc * 8;
  const unsigned short* bU0 = Bb + (size_t)srow * K + srcc * 8;

  f32x4 acc[8][2];
  #pragma unroll
  for (int i = 0; i < 8; ++i)
    #pragma unroll
    for (int j = 0; j < 2; ++j)
      #pragma unroll
      for (int r = 0; r < 4; ++r) acc[i][j][r] = 0.0f;

  #define STAGE_A2(tt, bb) do { \
    const int k0_ = (tt) * 32; \
    unsigned short* l_ = lds + (bb) * 12288 + wid * 512; \
    async_ld16(aU0 + k0_, l_); \
    async_ld16(aU1 + k0_, l_ + 4096); \
  } while (0)
  #define STAGE_B2(tt, bb) do { \
    const int k0_ = (tt) * 32; \
    unsigned short* l_ = lds + (bb) * 12288 + 8192 + wid * 512; \
    async_ld16(bU0 + k0_, l_); \
  } while (0)

  // prologue: tiles 0,1,2 -> bufs 0,1,2 (9 loads/thread)
  STAGE_A2(0, 0); STAGE_B2(0, 0);
  STAGE_A2(1, 1); STAGE_B2(1, 1);
  STAGE_A2(2, 2); STAGE_B2(2, 2);
  asm volatile("s_waitcnt vmcnt(6)" ::: "memory");   // tile 0 landed
  __builtin_amdgcn_s_barrier();

  for (int t = 0; t < NT; ++t) {
    const int buf = t & 3;
    const int pbuf = (t + 3) & 3;
    int ts = t + 3; if (ts >= NT) ts -= NT;   // wrapped source keeps vmcnt uniform
    const unsigned short* Ap = lds + buf * 12288;
    const unsigned short* Bp = Ap + 8192;
    short8 af[4], bfr[2];

    // ---- phase 0: C rows 0..63 of the wave's half ----
    #pragma unroll
    for (int i = 0; i < 4; ++i)
      af[i] = *(const short8*)(Ap + (wm * 128 + i * 16 + qm) * 32 + swc * 8);
    #pragma unroll
    for (int j = 0; j < 2; ++j)
      bfr[j] = *(const short8*)(Bp + (wn * 32 + j * 16 + qm) * 32 + swc * 8);
    STAGE_A2(ts, pbuf);
    __builtin_amdgcn_s_barrier();
    asm volatile("s_waitcnt lgkmcnt(0)" ::: "memory");
    __builtin_amdgcn_sched_barrier(0);
    __builtin_amdgcn_s_setprio(1);
    #pragma unroll
    for (int i = 0; i < 4; ++i)
      #pragma unroll
      for (int j = 0; j < 2; ++j)
        acc[i][j] = __builtin_amdgcn_mfma_f32_16x16x32_bf16(af[i], bfr[j], acc[i][j], 0, 0, 0);
    __builtin_amdgcn_s_setprio(0);
    __builtin_amdgcn_s_barrier();

    // ---- phase 1: C rows 64..127 (reuse bfr, re-read af) ----
    #pragma unroll
    for (int i = 0; i < 4; ++i)
      af[i] = *(const short8*)(Ap + (wm * 128 + (i + 4) * 16 + qm) * 32 + swc * 8);
    STAGE_B2(ts, pbuf);
    __builtin_amdgcn_s_barrier();
    asm volatile("s_waitcnt lgkmcnt(0)" ::: "memory");
    __builtin_amdgcn_sched_barrier(0);
    __builtin_amdgcn_s_setprio(1);
    #pragma unroll
    for (int i = 0; i < 4; ++i)
      #pragma unroll
      for (int j = 0; j < 2; ++j)
        acc[4 + i][j] = __builtin_amdgcn_mfma_f32_16x16x32_bf16(af[i], bfr[j], acc[4 + i][j], 0, 0, 0);
    __builtin_amdgcn_s_setprio(0);
    asm volatile("s_waitcnt vmcnt(6)" ::: "memory");   // tile t+1 guaranteed
    __builtin_amdgcn_s_barrier();
  }
  #undef STAGE_A2
  #undef STAGE_B2

  asm volatile("s_waitcnt vmcnt(0)" ::: "memory");

  float bcol[2];
  #pragma unroll
  for (int j = 0; j < 2; ++j)
    bcol[j] = bias[(size_t)e * N + colbase + wn * 32 + j * 16 + qm];

  #pragma unroll
  for (int i = 0; i < 8; ++i) {
    #pragma unroll
    for (int r = 0; r < 4; ++r) {
      const int row = rowbase + wm * 128 + i * 16 + qr * 4 + r;
      const int tk = slot_token[e * CAP + row];
      if (tk >= 0) {
        const float g = gate[tk];
        float* orow = Op + (size_t)tk * MDIM + colbase;
        #pragma unroll
        for (int j = 0; j < 2; ++j)
          orow[wn * 32 + j * 16 + qm] = g * (acc[i][j][r] + bcol[j]);
      }
    }
  }
}

extern "C" void kernel_launch(void* const* d_in, const int* in_sizes, int n_in,
                              void* d_out, int out_size, void* d_ws, size_t ws_size,
                              hipStream_t stream) {
  const float* x  = (const float*)d_in[0];
  const float* wg = (const float*)d_in[1];
  const float* w1 = (const float*)d_in[2];
  const float* b1 = (const float*)d_in[3];
  const float* w2 = (const float*)d_in[4];
  const float* b2 = (const float*)d_in[5];

  char* ws = (char*)d_ws;
  unsigned short* Abuf = (unsigned short*)ws;                 // E*C*M bf16    20,971,520 B
  unsigned short* H    = (unsigned short*)(ws + 20971520);    // E*C*DFF bf16  83,886,080 B
  unsigned short* Wt   = (unsigned short*)(ws + 104857600);   // E*4096*1024 bf16 = 67,108,864 B (reused W1T then W2T)
  int*   slot_token    = (int*)(ws + 171966464);              // E*C int       40,960 B
  int*   eidx          = (int*)(ws + 172007424);              // T int         32,768 B
  float* gate          = (float*)(ws + 172040192);            // T float       32,768 B
  int*   filled        = (int*)(ws + 172072960);              // E int

  // dropped tokens must output zeros; epilogue only writes kept rows
  hipMemsetAsync(d_out, 0, (size_t)out_size * sizeof(float), stream);

  gate_kernel<<<T_TOKENS, 64, 0, stream>>>(x, wg, eidx, gate);
  scan_kernel<<<1, 1024, 0, stream>>>(eidx, slot_token, filled);
  dispatch_kernel<<<NEXP * CAP, 256, 0, stream>>>(x, slot_token, Abuf);

  // W1 [E][M][DFF] fp32 -> Wt [E][DFF][M] bf16
  dim3 gc1(DFF_DIM / 64, MDIM / 64, NEXP);
  transpose_cvt_kernel<MDIM, DFF_DIM><<<gc1, 256, 0, stream>>>(w1, Wt);

  // GEMM1: 256^2 pipelined kernel, 640 blocks (16 colblk * 5 rowblk * 8 e)
  gemm1_256<<<dim3(640), 512, 0, stream>>>(Abuf, Wt, b1, H, filled);

  // W2 [E][DFF][M] fp32 -> Wt [E][M][DFF] bf16 (reuse buffer; stream-ordered after gemm1)
  dim3 gc2(MDIM / 64, DFF_DIM / 64, NEXP);
  transpose_cvt_kernel<DFF_DIM, MDIM><<<gc2, 256, 0, stream>>>(w2, Wt);

  // GEMM2: 256x128 pipelined kernel, 320 blocks (8 colblk * 5 rowblk * 8 e)
  gemm2_256<<<dim3(320), 512, 0, stream>>>(H, Wt, b2, (float*)d_out, slot_token, gate, filled);
}

// Round 4
// 561.102 us; speedup vs baseline: 1.0843x; 1.0843x over previous
//
#include <hip/hip_runtime.h>

#define T_TOKENS 8192
#define MDIM 1024
#define NEXP 8
#define DFF_DIM 4096
#define CAP 1280

typedef __attribute__((ext_vector_type(8))) short short8;
typedef __attribute__((ext_vector_type(4))) float f32x4;

__device__ inline unsigned short f2bf(float f) {
  unsigned u = __float_as_uint(f);
  u = u + 0x7fffu + ((u >> 16) & 1u);
  return (unsigned short)(u >> 16);
}

// async global->LDS DMA, 16B per lane. LDS dst must be wave-uniform base;
// lane i's data lands at base + i*16B (guide §5, m97/m104).
__device__ __forceinline__ void async_ld16(const void* g, void* l) {
  __builtin_amdgcn_global_load_lds(
      (__attribute__((address_space(1))) void*)const_cast<void*>(g),
      (__attribute__((address_space(3))) void*)l, 16, 0, 0);
}

// ---------------- gating: logits in fp64, softmax top-1 ----------------
__global__ __launch_bounds__(64) void gate_kernel(const float* __restrict__ x,
    const float* __restrict__ wg, int* __restrict__ eidx, float* __restrict__ gate)
{
  const int t = blockIdx.x;
  const int lane = threadIdx.x;
  const float* xr = x + (size_t)t * MDIM;
  double acc[NEXP];
  #pragma unroll
  for (int e = 0; e < NEXP; ++e) acc[e] = 0.0;
  for (int m = lane; m < MDIM; m += 64) {
    double xv = (double)xr[m];
    const float* wr = wg + (size_t)m * NEXP;
    #pragma unroll
    for (int e = 0; e < NEXP; ++e) acc[e] += xv * (double)wr[e];
  }
  #pragma unroll
  for (int off = 32; off > 0; off >>= 1) {
    #pragma unroll
    for (int e = 0; e < NEXP; ++e) acc[e] += __shfl_down(acc[e], off);
  }
  if (lane == 0) {
    double mx = acc[0]; int idx = 0;
    #pragma unroll
    for (int e = 1; e < NEXP; ++e) if (acc[e] > mx) { mx = acc[e]; idx = e; }
    double s = 0.0;
    #pragma unroll
    for (int e = 0; e < NEXP; ++e) s += exp(acc[e] - mx);
    eidx[t] = idx;
    gate[t] = (float)(1.0 / s);   // softmax prob of argmax expert
  }
}

// ---------------- order-preserving capacity scan (single block) ----------------
__global__ __launch_bounds__(1024) void scan_kernel(const int* __restrict__ eidx,
    int* __restrict__ slot_token, int* __restrict__ filled)
{
  __shared__ int hist[16][NEXP];
  __shared__ int wpre[16][NEXP];
  __shared__ int rtot[NEXP];
  __shared__ int base[NEXP];
  const int tid = threadIdx.x;
  const int w = tid >> 6, lane = tid & 63;
  for (int i = tid; i < NEXP * CAP; i += 1024) slot_token[i] = -1;
  if (tid < NEXP) base[tid] = 0;
  __syncthreads();
  const unsigned long long lt = (1ull << lane) - 1ull;
  for (int r = 0; r < T_TOKENS / 1024; ++r) {
    const int t = r * 1024 + tid;
    const int e = eidx[t];
    unsigned long long bal[NEXP];
    #pragma unroll
    for (int ee = 0; ee < NEXP; ++ee) bal[ee] = __ballot(e == ee);
    const int rank = __popcll(bal[e] & lt);
    if (lane < NEXP) hist[w][lane] = __popcll(bal[lane]);
    __syncthreads();
    if (tid < 16 * NEXP) {
      int ww = tid >> 3, ee = tid & 7, s = 0;
      for (int j = 0; j < ww; ++j) s += hist[j][ee];
      wpre[ww][ee] = s;
    }
    if (tid < NEXP) {
      int s = 0;
      for (int j = 0; j < 16; ++j) s += hist[j][tid];
      rtot[tid] = s;
    }
    __syncthreads();
    const int pos = base[e] + wpre[w][e] + rank;
    if (pos < CAP) slot_token[e * CAP + pos] = t;
    __syncthreads();
    if (tid < NEXP) base[tid] += rtot[tid];
    __syncthreads();
  }
  if (tid < NEXP) filled[tid] = (base[tid] < CAP) ? base[tid] : CAP;
}

// ---------------- dispatch: gather kept tokens into [E,C,M] bf16 ----------------
__global__ __launch_bounds__(256) void dispatch_kernel(const float* __restrict__ x,
    const int* __restrict__ slot_token, unsigned short* __restrict__ Abuf)
{
  const int row = blockIdx.x;
  const int tid = threadIdx.x;
  const int t = slot_token[row];
  unsigned short* dst = Abuf + (size_t)row * MDIM + tid * 4;
  if (t < 0) {
    ushort4 z; z.x = 0; z.y = 0; z.z = 0; z.w = 0;
    *(ushort4*)dst = z;
  } else {
    const float4 v = *(const float4*)(x + (size_t)t * MDIM + tid * 4);
    ushort4 h;
    h.x = f2bf(v.x); h.y = f2bf(v.y); h.z = f2bf(v.z); h.w = f2bf(v.w);
    *(ushort4*)dst = h;
  }
}

// ------------- weight transpose + fp32->bf16: src [R][Cc] -> dst [Cc][R] -------------
template<int R, int Cc>
__global__ __launch_bounds__(256) void transpose_cvt_kernel(
    const float* __restrict__ src, unsigned short* __restrict__ dst)
{
  __shared__ unsigned short tile[64][66];   // +2 pad: write-phase column reads ~2-way
  const int e = blockIdx.z;
  const int r0 = blockIdx.y * 64;
  const int c0 = blockIdx.x * 64;
  const int t = threadIdx.x;
  const float* S = src + (size_t)e * R * Cc;
  unsigned short* D = dst + (size_t)e * R * Cc;
  const int tr = t >> 4;         // 0..15
  const int tc = (t & 15) * 4;   // 0..60
  #pragma unroll
  for (int i = 0; i < 4; ++i) {
    const int row = i * 16 + tr;
    const float4 v = *(const float4*)(S + (size_t)(r0 + row) * Cc + c0 + tc);
    tile[row][tc + 0] = f2bf(v.x);
    tile[row][tc + 1] = f2bf(v.y);
    tile[row][tc + 2] = f2bf(v.z);
    tile[row][tc + 3] = f2bf(v.w);
  }
  __syncthreads();
  #pragma unroll
  for (int i = 0; i < 4; ++i) {
    const int crow = i * 16 + tr;   // src col index
    ushort4 o;
    o.x = tile[tc + 0][crow];
    o.y = tile[tc + 1][crow];
    o.z = tile[tc + 2][crow];
    o.w = tile[tc + 3][crow];
    *(ushort4*)(D + (size_t)(c0 + crow) * R + r0 + tc) = o;
  }
}

// =====================================================================
// Unified pipelined expert GEMM: 128x128 tile, BK=32, 256 threads
// (4 waves 2x2), 3 LDS buffers x 16KiB = 48KiB -> 3 blocks/CU resident
// (144KiB LDS, 12 waves/CU).  One barrier per K-step; counted vmcnt
// (steady-state vmcnt(4), never 0 in the loop); T2 chunk swizzle
// (verified 0 bank conflicts in rounds 1-2); T5 setprio; T1 bijective
// XCD swizzle (one expert per XCD; rowbase-fastest so consecutive
// blocks share the B col-panel in that XCD's L2).
//
// Pipeline invariants:
//  - tile t computes from buf (t%3); stage of tile t+2 targets (t+2)%3,
//    whose previous content (tile t-1) was fully ds_read before the
//    end-of-(t-1) barrier, and the stage is issued after that barrier
//    -> no WAR race.
//  - 4 global_load_lds per thread per tile; at end-of-tile-t the
//    outstanding loads are tiles t+1,t+2 (8); vmcnt(4) completes the
//    oldest 4 = all of tile t+1 (vmcnt retires in order, m135); the
//    s_barrier makes that guarantee cross-wave.
//  - no other VMEM ops inside the loop (keeps the vmcnt count exact).
//
// T2 swizzle: LDS row = 32 ushorts = 4 x 16B chunks. Stored chunk c of
// row r holds global chunk c ^ ((r>>1)&3) (involution). Staging keeps
// LDS linear and pre-swizzles the per-lane GLOBAL source chunk
// (srcc = (lane&3) ^ ((lane>>3)&3)); reads use swc = qr ^ ((qm>>1)&3).
// Quarter-wave bank enumeration: qm 0..7 cover all 32 banks exactly
// once, qm 8..15 repeat -> 2 dwords/bank = conflict-free (measured 0).
// =====================================================================
template<int MODE>
__global__ __launch_bounds__(256, 3) void gemm_pipe(
    const unsigned short* __restrict__ A,   // [E][CAP][K] bf16
    const unsigned short* __restrict__ Bt,  // [E][N][K] bf16 (pre-transposed W)
    const float* __restrict__ bias,         // [E][N]
    void* __restrict__ outp,
    const int* __restrict__ slot_token, const float* __restrict__ gate,
    const int* __restrict__ filled)
{
  constexpr int N = MODE ? MDIM : DFF_DIM;
  constexpr int K = MODE ? DFF_DIM : MDIM;
  constexpr int NT = K / 32;
  constexpr int ROWB = CAP / 128;          // 10
  constexpr int PERE = (N / 128) * ROWB;   // blocks per expert (320 or 80)

  // T1: grid = 8*PERE, id%8 selects chunk -> one expert per XCD.
  const int id = blockIdx.x;
  const int wk = (id & 7) * PERE + (id >> 3);
  const int e = wk / PERE;
  const int rem = wk % PERE;
  const int colbase = (rem / ROWB) * 128;
  const int rowbase = (rem % ROWB) * 128;  // rowbase fastest: B panel L2-hot
  if (rowbase >= filled[e]) return;        // block-uniform early exit

  // 3 buffers x (A 8KB + B 8KB) = 48 KiB
  __shared__ unsigned short lds[3 * 8192];

  const int tid = threadIdx.x;
  const int lane = tid & 63;
  const int wid = tid >> 6;                 // 0..3
  const int wm = (wid >> 1) * 64, wn = (wid & 1) * 64;
  const int qm = lane & 15, qr = lane >> 4;
  const int swc  = qr ^ ((qm >> 1) & 3);              // read-side chunk
  const int srcc = (lane & 3) ^ ((lane >> 3) & 3);    // stage-side source chunk

  const unsigned short* Ab = A + ((size_t)e * CAP + rowbase) * K;
  const unsigned short* Bb = Bt + ((size_t)e * N + colbase) * K;

  // staging unit = 64 rows x 32 k = 4KB = 256 threads x 16B (1 load/thread)
  const int srow = wid * 16 + (lane >> 2);            // 0..63 within unit
  const unsigned short* aU0 = Ab + (size_t)srow * K + srcc * 8;
  const unsigned short* aU1 = aU0 + (size_t)64 * K;
  const unsigned short* bU0 = Bb + (size_t)srow * K + srcc * 8;
  const unsigned short* bU1 = bU0 + (size_t)64 * K;

  f32x4 acc[4][4];
  #pragma unroll
  for (int i = 0; i < 4; ++i)
    #pragma unroll
    for (int j = 0; j < 4; ++j)
      #pragma unroll
      for (int r = 0; r < 4; ++r) acc[i][j][r] = 0.0f;

  // wave-uniform LDS dst bases (lane offset is implicit lane*16B in HW)
  #define STAGE(tt, bb) do { \
    const int k0_ = (tt) * 32; \
    unsigned short* l_ = lds + (bb) * 8192 + wid * 512; \
    async_ld16(aU0 + k0_, l_); \
    async_ld16(aU1 + k0_, l_ + 2048); \
    async_ld16(bU0 + k0_, l_ + 4096); \
    async_ld16(bU1 + k0_, l_ + 6144); \
  } while (0)

  // prologue: tiles 0,1 -> bufs 0,1 (8 loads/thread)
  STAGE(0, 0);
  STAGE(1, 1);
  asm volatile("s_waitcnt vmcnt(4)" ::: "memory");   // tile 0 landed
  __builtin_amdgcn_s_barrier();

  int buf = 0, nbuf = 1, pbuf = 2;
  for (int t = 0; t < NT; ++t) {
    int ts = t + 2; if (ts >= NT) ts -= NT;   // wrapped source keeps vmcnt
                                              // uniform; target buf is dead
                                              // for tiles >= NT (distinct residue).
    const unsigned short* Ap = lds + buf * 8192;
    const unsigned short* Bp = Ap + 4096;
    short8 af[4], bfr[4];
    #pragma unroll
    for (int i = 0; i < 4; ++i)
      af[i] = *(const short8*)(Ap + (wm + i * 16 + qm) * 32 + swc * 8);
    #pragma unroll
    for (int j = 0; j < 4; ++j)
      bfr[j] = *(const short8*)(Bp + (wn + j * 16 + qm) * 32 + swc * 8);
    STAGE(ts, pbuf);
    asm volatile("s_waitcnt lgkmcnt(0)" ::: "memory");
    __builtin_amdgcn_sched_barrier(0);        // rule #18: don't hoist MFMA past wait
    __builtin_amdgcn_s_setprio(1);
    #pragma unroll
    for (int i = 0; i < 4; ++i)
      #pragma unroll
      for (int j = 0; j < 4; ++j)
        acc[i][j] = __builtin_amdgcn_mfma_f32_16x16x32_bf16(af[i], bfr[j], acc[i][j], 0, 0, 0);
    __builtin_amdgcn_s_setprio(0);
    asm volatile("s_waitcnt vmcnt(4)" ::: "memory");   // tile t+1 guaranteed
    __builtin_amdgcn_s_barrier();
    const int tmp = buf; buf = nbuf; nbuf = pbuf; pbuf = tmp;
  }
  #undef STAGE

  // drain outstanding DMA before epilogue / exit
  asm volatile("s_waitcnt vmcnt(0)" ::: "memory");

  float bcol[4];
  #pragma unroll
  for (int j = 0; j < 4; ++j)
    bcol[j] = bias[(size_t)e * N + colbase + wn + j * 16 + qm];

  if (MODE == 0) {
    unsigned short* Hp = (unsigned short*)outp;
    #pragma unroll
    for (int i = 0; i < 4; ++i) {
      #pragma unroll
      for (int r = 0; r < 4; ++r) {
        const int row = rowbase + wm + i * 16 + qr * 4 + r;
        unsigned short* orow = Hp + ((size_t)e * CAP + row) * N + colbase;
        #pragma unroll
        for (int j = 0; j < 4; ++j) {
          float v = acc[i][j][r] + bcol[j];
          v = v > 0.0f ? v : 0.0f;
          orow[wn + j * 16 + qm] = f2bf(v);
        }
      }
    }
  } else {
    float* Op = (float*)outp;
    #pragma unroll
    for (int i = 0; i < 4; ++i) {
      #pragma unroll
      for (int r = 0; r < 4; ++r) {
        const int row = rowbase + wm + i * 16 + qr * 4 + r;
        const int tk = slot_token[e * CAP + row];
        if (tk >= 0) {
          const float g = gate[tk];
          float* orow = Op + (size_t)tk * MDIM + colbase;
          #pragma unroll
          for (int j = 0; j < 4; ++j)
            orow[wn + j * 16 + qm] = g * (acc[i][j][r] + bcol[j]);
        }
      }
    }
  }
}

extern "C" void kernel_launch(void* const* d_in, const int* in_sizes, int n_in,
                              void* d_out, int out_size, void* d_ws, size_t ws_size,
                              hipStream_t stream) {
  const float* x  = (const float*)d_in[0];
  const float* wg = (const float*)d_in[1];
  const float* w1 = (const float*)d_in[2];
  const float* b1 = (const float*)d_in[3];
  const float* w2 = (const float*)d_in[4];
  const float* b2 = (const float*)d_in[5];

  char* ws = (char*)d_ws;
  unsigned short* Abuf = (unsigned short*)ws;                 // E*C*M bf16    20,971,520 B
  unsigned short* H    = (unsigned short*)(ws + 20971520);    // E*C*DFF bf16  83,886,080 B
  unsigned short* Wt   = (unsigned short*)(ws + 104857600);   // E*4096*1024 bf16 = 67,108,864 B (reused W1T then W2T)
  int*   slot_token    = (int*)(ws + 171966464);              // E*C int       40,960 B
  int*   eidx          = (int*)(ws + 172007424);              // T int         32,768 B
  float* gate          = (float*)(ws + 172040192);            // T float       32,768 B
  int*   filled        = (int*)(ws + 172072960);              // E int

  // dropped tokens must output zeros; epilogue only writes kept rows
  hipMemsetAsync(d_out, 0, (size_t)out_size * sizeof(float), stream);

  gate_kernel<<<T_TOKENS, 64, 0, stream>>>(x, wg, eidx, gate);
  scan_kernel<<<1, 1024, 0, stream>>>(eidx, slot_token, filled);
  dispatch_kernel<<<NEXP * CAP, 256, 0, stream>>>(x, slot_token, Abuf);

  // W1 [E][M][DFF] fp32 -> Wt [E][DFF][M] bf16
  dim3 gc1(DFF_DIM / 64, MDIM / 64, NEXP);
  transpose_cvt_kernel<MDIM, DFF_DIM><<<gc1, 256, 0, stream>>>(w1, Wt);

  // GEMM1: 2560 blocks (32 colblk * 10 rowblk * 8 e), 3 blocks/CU resident
  gemm_pipe<0><<<dim3(2560), 256, 0, stream>>>(Abuf, Wt, b1, (void*)H,
                                               nullptr, nullptr, filled);

  // W2 [E][DFF][M] fp32 -> Wt [E][M][DFF] bf16 (reuse buffer; stream-ordered after gemm1)
  dim3 gc2(MDIM / 64, DFF_DIM / 64, NEXP);
  transpose_cvt_kernel<DFF_DIM, MDIM><<<gc2, 256, 0, stream>>>(w2, Wt);

  // GEMM2: 640 blocks (8 colblk * 10 rowblk * 8 e), ~all resident in one round
  gemm_pipe<1><<<dim3(640), 256, 0, stream>>>(H, Wt, b2, d_out,
                                              slot_token, gate, filled);
}